// Round 12
// baseline (124.426 us; speedup 1.0000x reference)
//
#include <hip/hip_runtime.h>

// Problem dims (fixed by reference)
#define BATCH  4096
#define IN_DIM 256
#define HID    512
#define NCOL   8192            // HID * STATES

// Main tiling: 128 rows x (2 x 64 cols) per block, 4 waves stacked on M
#define BM 128
#define BN 64

typedef __attribute__((ext_vector_type(8))) short bf16x8;
typedef __attribute__((ext_vector_type(4))) float f32x4;
typedef __attribute__((ext_vector_type(4))) float fvec4;   // clang-native, nt-compatible

typedef __attribute__((address_space(1))) const unsigned as1_uint;
typedef __attribute__((address_space(3))) unsigned       as3_uint;

// pack bf16(f0) into low16, bf16(f1) into high16 (truncation) — 1 v_perm_b32
__device__ __forceinline__ uint pack_hi(float f0, float f1) {
    return __builtin_amdgcn_perm(__builtin_bit_cast(uint, f1),
                                 __builtin_bit_cast(uint, f0), 0x07060302u);
}
__device__ __forceinline__ float hi_part(float f) {
    return __builtin_bit_cast(float, __builtin_bit_cast(uint, f) & 0xFFFF0000u);
}
__device__ __forceinline__ float tanh_fast(float x) {
    float e = __builtin_amdgcn_exp2f(x * 2.8853900817779268f); // 2*log2(e)
    float r = __builtin_amdgcn_rcpf(e + 1.0f);
    return __builtin_fmaf(-2.0f, r, 1.0f);
}
// split f[0..7] (k-consecutive) into hi/lo bf16x8 fragments
__device__ __forceinline__ void split8(const float* f, uint4& h, uint4& l) {
    h.x = pack_hi(f[0], f[1]); h.y = pack_hi(f[2], f[3]);
    h.z = pack_hi(f[4], f[5]); h.w = pack_hi(f[6], f[7]);
    l.x = pack_hi(f[0] - hi_part(f[0]), f[1] - hi_part(f[1]));
    l.y = pack_hi(f[2] - hi_part(f[2]), f[3] - hi_part(f[3]));
    l.z = pack_hi(f[4] - hi_part(f[4]), f[5] - hi_part(f[5]));
    l.w = pack_hi(f[6] - hi_part(f[6]), f[7] - hi_part(f[7]));
}

// Workspace layout (ushort elements):
//  whi [0, 2097152)  wlo [2097152, 4194304)   - 8192n x 256k, tiled
//  xhi [4194304, 5242880) xlo [5242880, 6291456) - 4096b x 256k, tiled
// tile layout: plane[((row>>4)*32 + koct)*128 + (row&15)*8 + j], k = koct*8+j
#define W_ELEMS  2097152
#define X_ELEMS  1048576
#define WS_NEED  (12u * 1024u * 1024u)

// ---- prep W: [k][n] f32 -> fragment-ready tiled bf16 hi/lo ----
__global__ __launch_bounds__(256) void prep_w_kernel(
    const float* __restrict__ W, ushort* __restrict__ whi, ushort* __restrict__ wlo)
{
    const int n    = blockIdx.x * 256 + threadIdx.x;   // 0..8191
    const int koct = blockIdx.y;                       // 0..31
    float f[8];
    #pragma unroll
    for (int j = 0; j < 8; ++j)
        f[j] = __builtin_nontemporal_load(&W[(size_t)(koct * 8 + j) * NCOL + n]);
    uint4 h, l;
    split8(f, h, l);
    const size_t o = ((size_t)((n >> 4) * 32 + koct) * 16 + (n & 15)) * 8;
    *(uint4*)(whi + o) = h;
    *(uint4*)(wlo + o) = l;
}

// ---- prep x: [b][k] f32 -> fragment-ready tiled bf16 hi/lo ----
__global__ __launch_bounds__(256) void prep_x_kernel(
    const float* __restrict__ x, ushort* __restrict__ xhi, ushort* __restrict__ xlo)
{
    const int b    = blockIdx.x * 256 + threadIdx.x;   // 0..4095
    const int koct = blockIdx.y;                       // 0..31
    float f[8];
    fvec4 v0 = __builtin_nontemporal_load((const fvec4*)&x[(size_t)b * IN_DIM + koct * 8]);
    fvec4 v1 = __builtin_nontemporal_load((const fvec4*)&x[(size_t)b * IN_DIM + koct * 8 + 4]);
    f[0] = v0.x; f[1] = v0.y; f[2] = v0.z; f[3] = v0.w;
    f[4] = v1.x; f[5] = v1.y; f[6] = v1.z; f[7] = v1.w;
    uint4 h, l;
    split8(f, h, l);
    const size_t o = ((size_t)((b >> 4) * 32 + koct) * 16 + (b & 15)) * 8;
    *(uint4*)(xhi + o) = h;
    *(uint4*)(xlo + o) = l;
}

// ---- main: 2 col-tiles per block; tile-A epilogue interleaved with tile-B
//      GEMM so HBM stream traffic spreads across compute phases. ----
// __launch_bounds__(256,3): cap ~170 regs (round 10/11: (256,4)'s 128 cap made
// the compiler sink all prefetches; (256,8) spilled catastrophically in r4).
// out_mean store must stay CACHED (nt on 4B scalars = ~8-16x write
// amplification, round 8). hq loads CACHED; out_new store nt.
__global__ __launch_bounds__(256, 3) void mqc_main_kernel(
    const ushort* __restrict__ xhi, const ushort* __restrict__ xlo,
    const ushort* __restrict__ whi, const ushort* __restrict__ wlo,
    const float* __restrict__ hq,
    float* __restrict__ out_mean, float* __restrict__ out_new)
{
    // one k-chunk (16 koct = 128 k) of B fragments: 4 ntiles x 16 kl x 16 l16 x 8
    __shared__ ushort sBh[8192], sBl[8192];    // 16 KiB + 16 KiB

    const int t     = threadIdx.x;
    const int lane  = t & 63;
    const int w     = t >> 6;           // wave 0..3 -> rows w*32..w*32+31
    const int lquad = lane >> 4;        // 0..3
    const int l16   = lane & 15;

    // XCD-clustered bijective block mapping (2048 = 8 xcd * 4 rowg * 64 pairg)
    const int wgid = blockIdx.x;
    const int xcd  = wgid & 7;
    const int q    = wgid >> 3;              // 0..255
    const int rowg = (xcd << 2) | (q & 3);   // 0..31
    const int pairg= q >> 2;                 // 0..63
    const int row0 = rowg * BM;
    const int col0 = pairg * 128;            // tiles at col0 and col0+64
    const int btile0 = (row0 >> 4) + w * 2;
    const int nt0A  = col0 >> 4;
    const int nt0B  = nt0A + 4;

    // Stage one k-chunk of B (both planes, 32 KB) via global_load_lds w16.
    #define STAGE(NT0, KOCT0) {                                                     \
        _Pragma("unroll")                                                           \
        for (int itc = 0; itc < 8; ++itc) {                                         \
            const int c  = itc * 4 + w;                                             \
            const int nt = (c >> 2) & 3;                                            \
            const int kl = (c & 3) * 4 + (lane >> 4);                               \
            const ushort* srcp = ((c >> 4) ? wlo : whi)                             \
                + ((size_t)((NT0) + nt) * 32 + (KOCT0) + kl) * 128 + (lane & 15) * 8; \
            ushort* dstp = ((c >> 4) ? sBl : sBh) + nt * 2048 + (c & 3) * 512;      \
            __builtin_amdgcn_global_load_lds((as1_uint*)srcp, (as3_uint*)dstp,      \
                                             16, 0, 0);                             \
        }                                                                           \
    }

    // prefetch A fragments for 2 k-steps (SL0, SL0+1) of chunk KOCT0 into regs
    #define APREF(AH, AL, KOCT0, SL0) {                                             \
        _Pragma("unroll")                                                           \
        for (int s = 0; s < 2; ++s) {                                               \
            const int koct = (KOCT0) + ((SL0) + s) * 4 + lquad;                     \
            _Pragma("unroll")                                                       \
            for (int mi = 0; mi < 2; ++mi) {                                        \
                const size_t o = ((size_t)(btile0 + mi) * 32 + koct) * 128 + l16 * 8; \
                AH[s][mi] = *(const bf16x8*)(xhi + o);                              \
                AL[s][mi] = *(const bf16x8*)(xlo + o);                              \
            }                                                                       \
        }                                                                           \
    }

    // 2 MFMA k-steps into ACC using prefetched A regs + staged B in LDS
    #define KSTEP2(ACC, AH, AL, SL0) {                                              \
        _Pragma("unroll")                                                           \
        for (int s = 0; s < 2; ++s) {                                               \
            const int bidx = (((SL0) + s) * 4 + lquad) * 128 + l16 * 8;             \
            bf16x8 bH[4], bL[4];                                                    \
            _Pragma("unroll")                                                       \
            for (int ni = 0; ni < 4; ++ni) {                                        \
                bH[ni] = *(const bf16x8*)(sBh + ni * 2048 + bidx);                  \
                bL[ni] = *(const bf16x8*)(sBl + ni * 2048 + bidx);                  \
            }                                                                       \
            _Pragma("unroll")                                                       \
            for (int mi = 0; mi < 2; ++mi)                                          \
                _Pragma("unroll")                                                   \
                for (int ni = 0; ni < 4; ++ni)                                      \
                    ACC[mi][ni] = __builtin_amdgcn_mfma_f32_16x16x32_bf16(bH[ni], AH[s][mi], ACC[mi][ni], 0, 0, 0); \
            _Pragma("unroll")                                                       \
            for (int mi = 0; mi < 2; ++mi)                                          \
                _Pragma("unroll")                                                   \
                for (int ni = 0; ni < 4; ++ni)                                      \
                    ACC[mi][ni] = __builtin_amdgcn_mfma_f32_16x16x32_bf16(bH[ni], AL[s][mi], ACC[mi][ni], 0, 0, 0); \
            _Pragma("unroll")                                                       \
            for (int mi = 0; mi < 2; ++mi)                                          \
                _Pragma("unroll")                                                   \
                for (int ni = 0; ni < 4; ++ni)                                      \
                    ACC[mi][ni] = __builtin_amdgcn_mfma_f32_16x16x32_bf16(bL[ni], AH[s][mi], ACC[mi][ni], 0, 0, 0); \
        }                                                                           \
    }

    #define HVLOAD(HV, COL0T) {                                                     \
        _Pragma("unroll")                                                           \
        for (int mi = 0; mi < 2; ++mi) {                                            \
            const int b = row0 + w * 32 + mi * 16 + l16;                            \
            _Pragma("unroll")                                                       \
            for (int ni = 0; ni < 4; ++ni) {                                        \
                const int n = (COL0T) + ni * 16 + lquad * 4;                        \
                HV[mi][ni] = *(const fvec4*)&hq[(size_t)b * NCOL + n];              \
            }                                                                       \
        }                                                                           \
    }

    // half-epilogue (one mi): tanh(C+0.9h), nt out_new store, cached out_mean
    // D[n][b]: n = COL0T+ni*16+4*lquad+reg, b = row0+w*32+MI*16+l16
    #define EPI_HALF(ACC, HV, COL0T, MI) {                                          \
        const int b = row0 + w * 32 + (MI) * 16 + l16;                              \
        _Pragma("unroll")                                                           \
        for (int ni = 0; ni < 4; ++ni) {                                            \
            const int n = (COL0T) + ni * 16 + lquad * 4;                            \
            fvec4 ov;                                                               \
            ov.x = tanh_fast(__builtin_fmaf(0.9f, HV[MI][ni].x, ACC[MI][ni][0]));   \
            ov.y = tanh_fast(__builtin_fmaf(0.9f, HV[MI][ni].y, ACC[MI][ni][1]));   \
            ov.z = tanh_fast(__builtin_fmaf(0.9f, HV[MI][ni].z, ACC[MI][ni][2]));   \
            ov.w = tanh_fast(__builtin_fmaf(0.9f, HV[MI][ni].w, ACC[MI][ni][3]));   \
            __builtin_nontemporal_store(ov, (fvec4*)&out_new[(size_t)b * NCOL + n]); \
            float ssum = (ov.x + ov.y) + (ov.z + ov.w);                             \
            ssum += __shfl_xor(ssum, 16);                                           \
            ssum += __shfl_xor(ssum, 32);                                           \
            if (lquad == 0)                                                         \
                out_mean[(size_t)b * HID + ((COL0T) >> 4) + ni] = ssum * 0.0625f;   \
        }                                                                           \
    }

    f32x4 accA[2][4] = {};
    f32x4 accB[2][4];
    bf16x8 AaH[2][2], AaL[2][2], AbH[2][2], AbL[2][2];
    fvec4 hv[2][4];

    // ================= TILE A (cols col0..col0+63) =================
    STAGE(nt0A, 0);
    APREF(AaH, AaL, 0, 0);
    __syncthreads();
    APREF(AbH, AbL, 0, 2);
    KSTEP2(accA, AaH, AaL, 0);
    KSTEP2(accA, AbH, AbL, 2);
    __syncthreads();
    STAGE(nt0A, 16);
    APREF(AaH, AaL, 16, 0);
    __syncthreads();
    APREF(AbH, AbL, 16, 2);
    KSTEP2(accA, AaH, AaL, 0);
    KSTEP2(accA, AbH, AbL, 2);
    __syncthreads();                    // tile-A LDS reads done before overwrite

    // ================= TILE B (cols col0+64..col0+127) =============
    // zero accB here (keeps its live range out of tile A)
    #pragma unroll
    for (int mi = 0; mi < 2; ++mi)
        #pragma unroll
        for (int ni = 0; ni < 4; ++ni)
            accB[mi][ni] = (f32x4){0.0f, 0.0f, 0.0f, 0.0f};

    STAGE(nt0B, 0);
    APREF(AaH, AaL, 0, 0);
    HVLOAD(hv, col0);                   // tile-A hq: shares the DMA barrier wait
    __syncthreads();
    APREF(AbH, AbL, 0, 2);
    KSTEP2(accB, AaH, AaL, 0);
    EPI_HALF(accA, hv, col0, 0);        // tile-A epilogue half 1, overlaps MFMA
    KSTEP2(accB, AbH, AbL, 2);
    __syncthreads();
    STAGE(nt0B, 16);
    APREF(AaH, AaL, 16, 0);
    __syncthreads();
    APREF(AbH, AbL, 16, 2);
    KSTEP2(accB, AaH, AaL, 0);
    EPI_HALF(accA, hv, col0, 1);        // tile-A epilogue half 2
    HVLOAD(hv, col0 + 64);              // tile-B hq, covered by last KSTEP2
    KSTEP2(accB, AbH, AbL, 2);
    EPI_HALF(accB, hv, col0 + 64, 0);
    EPI_HALF(accB, hv, col0 + 64, 1);

    #undef STAGE
    #undef APREF
    #undef KSTEP2
    #undef HVLOAD
    #undef EPI_HALF
}

// ================= fallback (round-5 proven kernel, used if ws too small) ======
#define BKF 64
__device__ __forceinline__ int swz(int row, int byteoff) {
    return byteoff ^ ((((row & 7) ^ ((row >> 3) & 7))) << 4);
}
__global__ __launch_bounds__(256, 4) void mqc_fallback_kernel(
    const float* __restrict__ x, const float* __restrict__ hq,
    const float* __restrict__ W,
    float* __restrict__ out_mean, float* __restrict__ out_new)
{
    __shared__ char sB[2 * BN * BKF * 2];
    char* const sB_hi = sB;
    char* const sB_lo = sB + BN * BKF * 2;
    const int t = threadIdx.x, lane = t & 63, w = t >> 6;
    const int lquad = lane >> 4, l16 = lane & 15;
    const int row0 = blockIdx.x * BM, col0 = blockIdx.y * BN;
    const int k0 = (t >> 4) * 4, n0 = (t & 15) * 4;
    f32x4 acc[2][4] = {};
    for (int kt = 0; kt < IN_DIM / BKF; ++kt) {
        float4 ax[2][2][2];
        #pragma unroll
        for (int mi = 0; mi < 2; ++mi)
            #pragma unroll
            for (int ks = 0; ks < 2; ++ks) {
                const float* p = &x[(size_t)(row0 + w * 32 + mi * 16 + l16) * IN_DIM
                                    + kt * BKF + ks * 32 + lquad * 8];
                ax[mi][ks][0] = *(const float4*)(p);
                ax[mi][ks][1] = *(const float4*)(p + 4);
            }
        float4 wrow[4];
        #pragma unroll
        for (int r = 0; r < 4; ++r)
            wrow[r] = *(const float4*)(&W[(size_t)(kt * BKF + k0 + r) * NCOL + col0 + n0]);
        #pragma unroll
        for (int c = 0; c < 4; ++c) {
            const float f0 = ((const float*)&wrow[0])[c];
            const float f1 = ((const float*)&wrow[1])[c];
            const float f2 = ((const float*)&wrow[2])[c];
            const float f3 = ((const float*)&wrow[3])[c];
            uint2 hv2, lv2;
            hv2.x = pack_hi(f0, f1); hv2.y = pack_hi(f2, f3);
            lv2.x = pack_hi(f0 - hi_part(f0), f1 - hi_part(f1));
            lv2.y = pack_hi(f2 - hi_part(f2), f3 - hi_part(f3));
            const int off = swz(n0 + c, (n0 + c) * (BKF * 2) + k0 * 2);
            *(uint2*)(sB_hi + off) = hv2;
            *(uint2*)(sB_lo + off) = lv2;
        }
        __syncthreads();
        #pragma unroll
        for (int ks = 0; ks < 2; ++ks) {
            bf16x8 aH[2], aL[2];
            #pragma unroll
            for (int mi = 0; mi < 2; ++mi) {
                uint4 h, l;
                split8((const float*)&ax[mi][ks][0], h, l);
                aH[mi] = __builtin_bit_cast(bf16x8, h);
                aL[mi] = __builtin_bit_cast(bf16x8, l);
            }
            const int kb = ks * 64 + lquad * 16;
            bf16x8 bH[4], bL[4];
            #pragma unroll
            for (int ni = 0; ni < 4; ++ni) {
                const int row = ni * 16 + l16;
                bH[ni] = *(const bf16x8*)(sB_hi + swz(row, row * (BKF * 2) + kb));
            }
            #pragma unroll
            for (int mi = 0; mi < 2; ++mi)
                #pragma unroll
                for (int ni = 0; ni < 4; ++ni)
                    acc[mi][ni] = __builtin_amdgcn_mfma_f32_16x16x32_bf16(bH[ni], aH[mi], acc[mi][ni], 0, 0, 0);
            #pragma unroll
            for (int mi = 0; mi < 2; ++mi)
                #pragma unroll
                for (int ni = 0; ni < 4; ++ni)
                    acc[mi][ni] = __builtin_amdgcn_mfma_f32_16x16x32_bf16(bH[ni], aL[mi], acc[mi][ni], 0, 0, 0);
            #pragma unroll
            for (int ni = 0; ni < 4; ++ni) {
                const int row = ni * 16 + l16;
                bL[ni] = *(const bf16x8*)(sB_lo + swz(row, row * (BKF * 2) + kb));
            }
            #pragma unroll
            for (int mi = 0; mi < 2; ++mi)
                #pragma unroll
                for (int ni = 0; ni < 4; ++ni)
                    acc[mi][ni] = __builtin_amdgcn_mfma_f32_16x16x32_bf16(bL[ni], aH[mi], acc[mi][ni], 0, 0, 0);
        }
        __syncthreads();
    }
    #pragma unroll
    for (int mi = 0; mi < 2; ++mi) {
        const int b = row0 + w * 32 + mi * 16 + l16;
        #pragma unroll
        for (int ni = 0; ni < 4; ++ni) {
            const int n = col0 + ni * 16 + lquad * 4;
            const float4 hv = *(const float4*)(&hq[(size_t)b * NCOL + n]);
            float4 ov;
            ov.x = tanh_fast(__builtin_fmaf(0.9f, hv.x, acc[mi][ni][0]));
            ov.y = tanh_fast(__builtin_fmaf(0.9f, hv.y, acc[mi][ni][1]));
            ov.z = tanh_fast(__builtin_fmaf(0.9f, hv.z, acc[mi][ni][2]));
            ov.w = tanh_fast(__builtin_fmaf(0.9f, hv.w, acc[mi][ni][3]));
            *(float4*)(&out_new[(size_t)b * NCOL + n]) = ov;
            float s = (ov.x + ov.y) + (ov.z + ov.w);
            s += __shfl_xor(s, 16);
            s += __shfl_xor(s, 32);
            if (lquad == 0)
                out_mean[(size_t)b * HID + (col0 >> 4) + ni] = s * 0.0625f;
        }
    }
}

extern "C" void kernel_launch(void* const* d_in, const int* in_sizes, int n_in,
                              void* d_out, int out_size, void* d_ws, size_t ws_size,
                              hipStream_t stream) {
    const float* x  = (const float*)d_in[0];   // [4096, 256]
    const float* hq = (const float*)d_in[1];   // [4096, 512, 16]
    const float* W  = (const float*)d_in[2];   // [256, 512, 16]

    float* out_mean = (float*)d_out;                          // [4096, 512]
    float* out_new  = (float*)d_out + (size_t)BATCH * HID;    // [4096, 512, 16]

    if (ws_size >= WS_NEED) {
        ushort* whi = (ushort*)d_ws;
        ushort* wlo = whi + W_ELEMS;
        ushort* xhi = wlo + W_ELEMS;
        ushort* xlo = xhi + X_ELEMS;
        prep_w_kernel<<<dim3(NCOL / 256, IN_DIM / 8), 256, 0, stream>>>(W, whi, wlo);
        prep_x_kernel<<<dim3(BATCH / 256, IN_DIM / 8), 256, 0, stream>>>(x, xhi, xlo);
        mqc_main_kernel<<<dim3(BATCH * NCOL / (BM * 2 * BN)), 256, 0, stream>>>(
            xhi, xlo, whi, wlo, hq, out_mean, out_new);
    } else {
        mqc_fallback_kernel<<<dim3(BATCH / BM, NCOL / BN), 256, 0, stream>>>(
            x, hq, W, out_mean, out_new);
    }
}

// Round 13
// 109.355 us; speedup vs baseline: 1.1378x; 1.1378x over previous
//
#include <hip/hip_runtime.h>

// Problem dims (fixed by reference)
#define BATCH  4096
#define IN_DIM 256
#define HID    512
#define NCOL   8192            // HID * STATES

// Main tiling: 128x64 block tile, 4 waves stacked on M (32 rows each)
#define BM 128
#define BN 64

typedef __attribute__((ext_vector_type(8))) short bf16x8;
typedef __attribute__((ext_vector_type(4))) float f32x4;
typedef __attribute__((ext_vector_type(4))) float fvec4;   // clang-native, nt-compatible

typedef __attribute__((address_space(1))) const unsigned as1_uint;
typedef __attribute__((address_space(3))) unsigned       as3_uint;

// pack bf16(f0) into low16, bf16(f1) into high16 (truncation) — 1 v_perm_b32
__device__ __forceinline__ uint pack_hi(float f0, float f1) {
    return __builtin_amdgcn_perm(__builtin_bit_cast(uint, f1),
                                 __builtin_bit_cast(uint, f0), 0x07060302u);
}
__device__ __forceinline__ float hi_part(float f) {
    return __builtin_bit_cast(float, __builtin_bit_cast(uint, f) & 0xFFFF0000u);
}
__device__ __forceinline__ float tanh_fast(float x) {
    float e = __builtin_amdgcn_exp2f(x * 2.8853900817779268f); // 2*log2(e)
    float r = __builtin_amdgcn_rcpf(e + 1.0f);
    return __builtin_fmaf(-2.0f, r, 1.0f);
}
// split f[0..7] (k-consecutive) into hi/lo bf16x8 fragments
__device__ __forceinline__ void split8(const float* f, uint4& h, uint4& l) {
    h.x = pack_hi(f[0], f[1]); h.y = pack_hi(f[2], f[3]);
    h.z = pack_hi(f[4], f[5]); h.w = pack_hi(f[6], f[7]);
    l.x = pack_hi(f[0] - hi_part(f[0]), f[1] - hi_part(f[1]));
    l.y = pack_hi(f[2] - hi_part(f[2]), f[3] - hi_part(f[3]));
    l.z = pack_hi(f[4] - hi_part(f[4]), f[5] - hi_part(f[5]));
    l.w = pack_hi(f[6] - hi_part(f[6]), f[7] - hi_part(f[7]));
}

// Workspace layout (ushort elements):
//  whi [0, 2097152)  wlo [2097152, 4194304)   - 8192n x 256k, tiled
//  xhi [4194304, 5242880) xlo [5242880, 6291456) - 4096b x 256k, tiled
// tile layout: plane[((row>>4)*32 + koct)*128 + (row&15)*8 + j], k = koct*8+j
#define W_ELEMS  2097152
#define X_ELEMS  1048576
#define WS_NEED  (12u * 1024u * 1024u)

// ---- prep W: [k][n] f32 -> fragment-ready tiled bf16 hi/lo ----
__global__ __launch_bounds__(256) void prep_w_kernel(
    const float* __restrict__ W, ushort* __restrict__ whi, ushort* __restrict__ wlo)
{
    const int n    = blockIdx.x * 256 + threadIdx.x;   // 0..8191
    const int koct = blockIdx.y;                       // 0..31
    float f[8];
    #pragma unroll
    for (int j = 0; j < 8; ++j)
        f[j] = __builtin_nontemporal_load(&W[(size_t)(koct * 8 + j) * NCOL + n]);
    uint4 h, l;
    split8(f, h, l);
    const size_t o = ((size_t)((n >> 4) * 32 + koct) * 16 + (n & 15)) * 8;
    *(uint4*)(whi + o) = h;
    *(uint4*)(wlo + o) = l;
}

// ---- prep x: [b][k] f32 -> fragment-ready tiled bf16 hi/lo ----
__global__ __launch_bounds__(256) void prep_x_kernel(
    const float* __restrict__ x, ushort* __restrict__ xhi, ushort* __restrict__ xlo)
{
    const int b    = blockIdx.x * 256 + threadIdx.x;   // 0..4095
    const int koct = blockIdx.y;                       // 0..31
    float f[8];
    fvec4 v0 = __builtin_nontemporal_load((const fvec4*)&x[(size_t)b * IN_DIM + koct * 8]);
    fvec4 v1 = __builtin_nontemporal_load((const fvec4*)&x[(size_t)b * IN_DIM + koct * 8 + 4]);
    f[0] = v0.x; f[1] = v0.y; f[2] = v0.z; f[3] = v0.w;
    f[4] = v1.x; f[5] = v1.y; f[6] = v1.z; f[7] = v1.w;
    uint4 h, l;
    split8(f, h, l);
    const size_t o = ((size_t)((b >> 4) * 32 + koct) * 16 + (b & 15)) * 8;
    *(uint4*)(xhi + o) = h;
    *(uint4*)(xlo + o) = l;
}

// ---- main: B via LDS DMA, A via register-prefetch ping-pong (round-11 body) ----
// __launch_bounds__(256,4): round-11 measured demand = 64 VGPR + 32 acc AGPR
// = 96 unified <= 128 cap, so prefetches should survive AND 4 blocks/CU fit
// (LDS 32KB x 4 = 128KB). Tripwires: VGPR_Count < 56 => compiler sank the
// prefetches (go back to (256,3)); hbm_bytes > 3.4e8 => spills (same).
// Round 4 proved (256,8) spills catastrophically. Round 12 proved dual-tile
// (2 live accumulator sets) spills at any bound — do not reintroduce.
// out_mean store must stay CACHED (nt on 4B scalars caused ~8-16x write
// amplification in round 8). hq loads CACHED (L3 absorbs the stream).
// out_new store CACHED: nt store forces endpgm to wait on full HBM drain
// (~600-900cyc x 16 block-generations/CU); L2 completes it in ~100-200cyc.
__global__ __launch_bounds__(256, 4) void mqc_main_kernel(
    const ushort* __restrict__ xhi, const ushort* __restrict__ xlo,
    const ushort* __restrict__ whi, const ushort* __restrict__ wlo,
    const float* __restrict__ hq,
    float* __restrict__ out_mean, float* __restrict__ out_new)
{
    // one k-chunk (16 koct = 128 k) of B fragments: 4 ntiles x 16 kl x 16 l16 x 8
    __shared__ ushort sBh[8192], sBl[8192];    // 16 KiB + 16 KiB

    const int t     = threadIdx.x;
    const int lane  = t & 63;
    const int w     = t >> 6;           // wave 0..3 -> rows w*32..w*32+31
    const int lquad = lane >> 4;        // 0..3
    const int l16   = lane & 15;

    // XCD-clustered bijective block mapping (4096 = 8 xcd * 4 rowg * 128 colg)
    const int wgid = blockIdx.x;
    const int xcd  = wgid & 7;
    const int q    = wgid >> 3;
    const int rowg = (xcd << 2) | (q & 3);   // 0..31
    const int colg = q >> 2;                 // 0..127
    const int row0 = rowg * BM;
    const int col0 = colg * BN;
    const int btile0 = (row0 >> 4) + w * 2;
    const int ntile0 = col0 >> 4;

    f32x4 acc[2][4] = {};               // [mi][ni]; D[n][b]: row=n, col=b

    // Stage one k-chunk of B (both planes, 32 KB) via global_load_lds w16.
    #define STAGE(KOCT0) {                                                          \
        _Pragma("unroll")                                                           \
        for (int itc = 0; itc < 8; ++itc) {                                         \
            const int c  = itc * 4 + w;                                             \
            const int nt = (c >> 2) & 3;                                            \
            const int kl = (c & 3) * 4 + (lane >> 4);                               \
            const ushort* srcp = ((c >> 4) ? wlo : whi)                             \
                + ((size_t)(ntile0 + nt) * 32 + (KOCT0) + kl) * 128 + (lane & 15) * 8; \
            ushort* dstp = ((c >> 4) ? sBl : sBh) + nt * 2048 + (c & 3) * 512;      \
            __builtin_amdgcn_global_load_lds((as1_uint*)srcp, (as3_uint*)dstp,      \
                                             16, 0, 0);                             \
        }                                                                           \
    }

    // prefetch A fragments for 2 k-steps (SL0, SL0+1) of chunk KOCT0 into regs
    #define APREF(AH, AL, KOCT0, SL0) {                                             \
        _Pragma("unroll")                                                           \
        for (int s = 0; s < 2; ++s) {                                               \
            const int koct = (KOCT0) + ((SL0) + s) * 4 + lquad;                     \
            _Pragma("unroll")                                                       \
            for (int mi = 0; mi < 2; ++mi) {                                        \
                const size_t o = ((size_t)(btile0 + mi) * 32 + koct) * 128 + l16 * 8; \
                AH[s][mi] = *(const bf16x8*)(xhi + o);                              \
                AL[s][mi] = *(const bf16x8*)(xlo + o);                              \
            }                                                                       \
        }                                                                           \
    }

    // 2 MFMA k-steps (SL0, SL0+1) using prefetched A regs + staged B in LDS
    #define KSTEP2(AH, AL, SL0) {                                                   \
        _Pragma("unroll")                                                           \
        for (int s = 0; s < 2; ++s) {                                               \
            const int bidx = (((SL0) + s) * 4 + lquad) * 128 + l16 * 8;             \
            bf16x8 bH[4], bL[4];                                                    \
            _Pragma("unroll")                                                       \
            for (int ni = 0; ni < 4; ++ni) {                                        \
                bH[ni] = *(const bf16x8*)(sBh + ni * 2048 + bidx);                  \
                bL[ni] = *(const bf16x8*)(sBl + ni * 2048 + bidx);                  \
            }                                                                       \
            _Pragma("unroll")                                                       \
            for (int mi = 0; mi < 2; ++mi)                                          \
                _Pragma("unroll")                                                   \
                for (int ni = 0; ni < 4; ++ni)                                      \
                    acc[mi][ni] = __builtin_amdgcn_mfma_f32_16x16x32_bf16(bH[ni], AH[s][mi], acc[mi][ni], 0, 0, 0); \
            _Pragma("unroll")                                                       \
            for (int mi = 0; mi < 2; ++mi)                                          \
                _Pragma("unroll")                                                   \
                for (int ni = 0; ni < 4; ++ni)                                      \
                    acc[mi][ni] = __builtin_amdgcn_mfma_f32_16x16x32_bf16(bH[ni], AL[s][mi], acc[mi][ni], 0, 0, 0); \
            _Pragma("unroll")                                                       \
            for (int mi = 0; mi < 2; ++mi)                                          \
                _Pragma("unroll")                                                   \
                for (int ni = 0; ni < 4; ++ni)                                      \
                    acc[mi][ni] = __builtin_amdgcn_mfma_f32_16x16x32_bf16(bL[ni], AH[s][mi], acc[mi][ni], 0, 0, 0); \
        }                                                                           \
    }

    bf16x8 AaH[2][2], AaL[2][2], AbH[2][2], AbL[2][2];
    fvec4 hv[2][4];

    // ---- chunk 0 (koct 0..15) ----
    STAGE(0);
    APREF(AaH, AaL, 0, 0);          // A for ksteps 0,1 — in flight with DMA
    __syncthreads();                // drains DMA + A loads
    APREF(AbH, AbL, 0, 2);          // A for ksteps 2,3 — hidden under KSTEP2
    KSTEP2(AaH, AaL, 0);
    KSTEP2(AbH, AbL, 2);
    __syncthreads();                // chunk-0 LDS reads done before overwrite
    // ---- chunk 1 (koct 16..31) ----
    STAGE(16);
    APREF(AaH, AaL, 16, 0);
    __syncthreads();
    APREF(AbH, AbL, 16, 2);
    KSTEP2(AaH, AaL, 0);
    // epilogue hq prefetch (cached): covered by the remaining 48 MFMAs
    #pragma unroll
    for (int mi = 0; mi < 2; ++mi) {
        const int b = row0 + w * 32 + mi * 16 + l16;
        #pragma unroll
        for (int ni = 0; ni < 4; ++ni) {
            const int n = col0 + ni * 16 + lquad * 4;
            hv[mi][ni] = *(const fvec4*)&hq[(size_t)b * NCOL + n];
        }
    }
    KSTEP2(AbH, AbL, 2);
    #undef STAGE
    #undef APREF
    #undef KSTEP2

    // ---- fused epilogue: tanh(C + 0.9*h), cached out_new + out_mean stores.
    //      D[n][b]: n = col0+ni*16+4*lquad+reg, b = row0+w*32+mi*16+l16
    #pragma unroll
    for (int mi = 0; mi < 2; ++mi) {
        const int b = row0 + w * 32 + mi * 16 + l16;
        #pragma unroll
        for (int ni = 0; ni < 4; ++ni) {
            const int n = col0 + ni * 16 + lquad * 4;
            fvec4 ov;
            ov.x = tanh_fast(__builtin_fmaf(0.9f, hv[mi][ni].x, acc[mi][ni][0]));
            ov.y = tanh_fast(__builtin_fmaf(0.9f, hv[mi][ni].y, acc[mi][ni][1]));
            ov.z = tanh_fast(__builtin_fmaf(0.9f, hv[mi][ni].z, acc[mi][ni][2]));
            ov.w = tanh_fast(__builtin_fmaf(0.9f, hv[mi][ni].w, acc[mi][ni][3]));
            *(fvec4*)&out_new[(size_t)b * NCOL + n] = ov;
            float s = (ov.x + ov.y) + (ov.z + ov.w);
            s += __shfl_xor(s, 16);
            s += __shfl_xor(s, 32);
            if (lquad == 0)
                out_mean[(size_t)b * HID + (col0 >> 4) + ni] = s * 0.0625f;
        }
    }
}

// ================= fallback (round-5 proven kernel, used if ws too small) ======
#define BKF 64
__device__ __forceinline__ int swz(int row, int byteoff) {
    return byteoff ^ ((((row & 7) ^ ((row >> 3) & 7))) << 4);
}
__global__ __launch_bounds__(256, 4) void mqc_fallback_kernel(
    const float* __restrict__ x, const float* __restrict__ hq,
    const float* __restrict__ W,
    float* __restrict__ out_mean, float* __restrict__ out_new)
{
    __shared__ char sB[2 * BN * BKF * 2];
    char* const sB_hi = sB;
    char* const sB_lo = sB + BN * BKF * 2;
    const int t = threadIdx.x, lane = t & 63, w = t >> 6;
    const int lquad = lane >> 4, l16 = lane & 15;
    const int row0 = blockIdx.x * BM, col0 = blockIdx.y * BN;
    const int k0 = (t >> 4) * 4, n0 = (t & 15) * 4;
    f32x4 acc[2][4] = {};
    for (int kt = 0; kt < IN_DIM / BKF; ++kt) {
        float4 ax[2][2][2];
        #pragma unroll
        for (int mi = 0; mi < 2; ++mi)
            #pragma unroll
            for (int ks = 0; ks < 2; ++ks) {
                const float* p = &x[(size_t)(row0 + w * 32 + mi * 16 + l16) * IN_DIM
                                    + kt * BKF + ks * 32 + lquad * 8];
                ax[mi][ks][0] = *(const float4*)(p);
                ax[mi][ks][1] = *(const float4*)(p + 4);
            }
        float4 wrow[4];
        #pragma unroll
        for (int r = 0; r < 4; ++r)
            wrow[r] = *(const float4*)(&W[(size_t)(kt * BKF + k0 + r) * NCOL + col0 + n0]);
        #pragma unroll
        for (int c = 0; c < 4; ++c) {
            const float f0 = ((const float*)&wrow[0])[c];
            const float f1 = ((const float*)&wrow[1])[c];
            const float f2 = ((const float*)&wrow[2])[c];
            const float f3 = ((const float*)&wrow[3])[c];
            uint2 hv2, lv2;
            hv2.x = pack_hi(f0, f1); hv2.y = pack_hi(f2, f3);
            lv2.x = pack_hi(f0 - hi_part(f0), f1 - hi_part(f1));
            lv2.y = pack_hi(f2 - hi_part(f2), f3 - hi_part(f3));
            const int off = swz(n0 + c, (n0 + c) * (BKF * 2) + k0 * 2);
            *(uint2*)(sB_hi + off) = hv2;
            *(uint2*)(sB_lo + off) = lv2;
        }
        __syncthreads();
        #pragma unroll
        for (int ks = 0; ks < 2; ++ks) {
            bf16x8 aH[2], aL[2];
            #pragma unroll
            for (int mi = 0; mi < 2; ++mi) {
                uint4 h, l;
                split8((const float*)&ax[mi][ks][0], h, l);
                aH[mi] = __builtin_bit_cast(bf16x8, h);
                aL[mi] = __builtin_bit_cast(bf16x8, l);
            }
            const int kb = ks * 64 + lquad * 16;
            bf16x8 bH[4], bL[4];
            #pragma unroll
            for (int ni = 0; ni < 4; ++ni) {
                const int row = ni * 16 + l16;
                bH[ni] = *(const bf16x8*)(sB_hi + swz(row, row * (BKF * 2) + kb));
            }
            #pragma unroll
            for (int mi = 0; mi < 2; ++mi)
                #pragma unroll
                for (int ni = 0; ni < 4; ++ni)
                    acc[mi][ni] = __builtin_amdgcn_mfma_f32_16x16x32_bf16(bH[ni], aH[mi], acc[mi][ni], 0, 0, 0);
            #pragma unroll
            for (int mi = 0; mi < 2; ++mi)
                #pragma unroll
                for (int ni = 0; ni < 4; ++ni)
                    acc[mi][ni] = __builtin_amdgcn_mfma_f32_16x16x32_bf16(bH[ni], aL[mi], acc[mi][ni], 0, 0, 0);
            #pragma unroll
            for (int ni = 0; ni < 4; ++ni) {
                const int row = ni * 16 + l16;
                bL[ni] = *(const bf16x8*)(sB_lo + swz(row, row * (BKF * 2) + kb));
            }
            #pragma unroll
            for (int mi = 0; mi < 2; ++mi)
                #pragma unroll
                for (int ni = 0; ni < 4; ++ni)
                    acc[mi][ni] = __builtin_amdgcn_mfma_f32_16x16x32_bf16(bL[ni], aH[mi], acc[mi][ni], 0, 0, 0);
        }
        __syncthreads();
    }
    #pragma unroll
    for (int mi = 0; mi < 2; ++mi) {
        const int b = row0 + w * 32 + mi * 16 + l16;
        #pragma unroll
        for (int ni = 0; ni < 4; ++ni) {
            const int n = col0 + ni * 16 + lquad * 4;
            const float4 hv = *(const float4*)(&hq[(size_t)b * NCOL + n]);
            float4 ov;
            ov.x = tanh_fast(__builtin_fmaf(0.9f, hv.x, acc[mi][ni][0]));
            ov.y = tanh_fast(__builtin_fmaf(0.9f, hv.y, acc[mi][ni][1]));
            ov.z = tanh_fast(__builtin_fmaf(0.9f, hv.z, acc[mi][ni][2]));
            ov.w = tanh_fast(__builtin_fmaf(0.9f, hv.w, acc[mi][ni][3]));
            *(float4*)(&out_new[(size_t)b * NCOL + n]) = ov;
            float s = (ov.x + ov.y) + (ov.z + ov.w);
            s += __shfl_xor(s, 16);
            s += __shfl_xor(s, 32);
            if (lquad == 0)
                out_mean[(size_t)b * HID + (col0 >> 4) + ni] = s * 0.0625f;
        }
    }
}

extern "C" void kernel_launch(void* const* d_in, const int* in_sizes, int n_in,
                              void* d_out, int out_size, void* d_ws, size_t ws_size,
                              hipStream_t stream) {
    const float* x  = (const float*)d_in[0];   // [4096, 256]
    const float* hq = (const float*)d_in[1];   // [4096, 512, 16]
    const float* W  = (const float*)d_in[2];   // [256, 512, 16]

    float* out_mean = (float*)d_out;                          // [4096, 512]
    float* out_new  = (float*)d_out + (size_t)BATCH * HID;    // [4096, 512, 16]

    if (ws_size >= WS_NEED) {
        ushort* whi = (ushort*)d_ws;
        ushort* wlo = whi + W_ELEMS;
        ushort* xhi = wlo + W_ELEMS;
        ushort* xlo = xhi + X_ELEMS;
        prep_w_kernel<<<dim3(NCOL / 256, IN_DIM / 8), 256, 0, stream>>>(W, whi, wlo);
        prep_x_kernel<<<dim3(BATCH / 256, IN_DIM / 8), 256, 0, stream>>>(x, xhi, xlo);
        mqc_main_kernel<<<dim3(BATCH * NCOL / (BM * BN)), 256, 0, stream>>>(
            xhi, xlo, whi, wlo, hq, out_mean, out_new);
    } else {
        mqc_fallback_kernel<<<dim3(BATCH / BM, NCOL / BN), 256, 0, stream>>>(
            x, hq, W, out_mean, out_new);
    }
}

// Round 14
// 93.142 us; speedup vs baseline: 1.3359x; 1.1741x over previous
//
#include <hip/hip_runtime.h>

// Problem dims (fixed by reference)
#define BATCH  4096
#define IN_DIM 256
#define HID    512
#define NCOL   8192            // HID * STATES

// Main tiling: 128x64 block tile, 4 waves stacked on M (32 rows each)
#define BM 128
#define BN 64

typedef __attribute__((ext_vector_type(8))) short bf16x8;
typedef __attribute__((ext_vector_type(4))) float f32x4;
typedef __attribute__((ext_vector_type(4))) float fvec4;   // clang-native, nt-compatible

typedef __attribute__((address_space(1))) const unsigned as1_uint;
typedef __attribute__((address_space(3))) unsigned       as3_uint;

// pack bf16(f0) into low16, bf16(f1) into high16 (truncation) — 1 v_perm_b32
__device__ __forceinline__ uint pack_hi(float f0, float f1) {
    return __builtin_amdgcn_perm(__builtin_bit_cast(uint, f1),
                                 __builtin_bit_cast(uint, f0), 0x07060302u);
}
__device__ __forceinline__ float hi_part(float f) {
    return __builtin_bit_cast(float, __builtin_bit_cast(uint, f) & 0xFFFF0000u);
}
__device__ __forceinline__ float tanh_fast(float x) {
    float e = __builtin_amdgcn_exp2f(x * 2.8853900817779268f); // 2*log2(e)
    float r = __builtin_amdgcn_rcpf(e + 1.0f);
    return __builtin_fmaf(-2.0f, r, 1.0f);
}
// split f[0..7] (k-consecutive) into hi/lo bf16x8 fragments
__device__ __forceinline__ void split8(const float* f, uint4& h, uint4& l) {
    h.x = pack_hi(f[0], f[1]); h.y = pack_hi(f[2], f[3]);
    h.z = pack_hi(f[4], f[5]); h.w = pack_hi(f[6], f[7]);
    l.x = pack_hi(f[0] - hi_part(f[0]), f[1] - hi_part(f[1]));
    l.y = pack_hi(f[2] - hi_part(f[2]), f[3] - hi_part(f[3]));
    l.z = pack_hi(f[4] - hi_part(f[4]), f[5] - hi_part(f[5]));
    l.w = pack_hi(f[6] - hi_part(f[6]), f[7] - hi_part(f[7]));
}

// Workspace layout (ushort elements):
//  whi [0, 2097152)  wlo [2097152, 4194304)   - 8192n x 256k, tiled
//  xhi [4194304, 5242880) xlo [5242880, 6291456) - 4096b x 256k, tiled
// tile layout: plane[((row>>4)*32 + koct)*128 + (row&15)*8 + j], k = koct*8+j
#define W_ELEMS  2097152
#define X_ELEMS  1048576
#define WS_NEED  (12u * 1024u * 1024u)

// ---- prep W: [k][n] f32 -> fragment-ready tiled bf16 hi/lo ----
__global__ __launch_bounds__(256) void prep_w_kernel(
    const float* __restrict__ W, ushort* __restrict__ whi, ushort* __restrict__ wlo)
{
    const int n    = blockIdx.x * 256 + threadIdx.x;   // 0..8191
    const int koct = blockIdx.y;                       // 0..31
    float f[8];
    #pragma unroll
    for (int j = 0; j < 8; ++j)
        f[j] = __builtin_nontemporal_load(&W[(size_t)(koct * 8 + j) * NCOL + n]);
    uint4 h, l;
    split8(f, h, l);
    const size_t o = ((size_t)((n >> 4) * 32 + koct) * 16 + (n & 15)) * 8;
    *(uint4*)(whi + o) = h;
    *(uint4*)(wlo + o) = l;
}

// ---- prep x: [b][k] f32 -> fragment-ready tiled bf16 hi/lo ----
__global__ __launch_bounds__(256) void prep_x_kernel(
    const float* __restrict__ x, ushort* __restrict__ xhi, ushort* __restrict__ xlo)
{
    const int b    = blockIdx.x * 256 + threadIdx.x;   // 0..4095
    const int koct = blockIdx.y;                       // 0..31
    float f[8];
    fvec4 v0 = __builtin_nontemporal_load((const fvec4*)&x[(size_t)b * IN_DIM + koct * 8]);
    fvec4 v1 = __builtin_nontemporal_load((const fvec4*)&x[(size_t)b * IN_DIM + koct * 8 + 4]);
    f[0] = v0.x; f[1] = v0.y; f[2] = v0.z; f[3] = v0.w;
    f[4] = v1.x; f[5] = v1.y; f[6] = v1.z; f[7] = v1.w;
    uint4 h, l;
    split8(f, h, l);
    const size_t o = ((size_t)((b >> 4) * 32 + koct) * 16 + (b & 15)) * 8;
    *(uint4*)(xhi + o) = h;
    *(uint4*)(xlo + o) = l;
}

// ---- main: B via LDS DMA, A via register-prefetch ping-pong (round-11 body,
//      hq prefetch hoisted into chunk 0) ----
// __launch_bounds__(256,3): cap ~170 regs. Round 13 A/B showed (256,4)+cached
// regressed the BENCH (93->109us) despite better rocprof — revert to the r11
// config and change only the hv timing. Round 4: (256,8) spills. Round 12:
// dual-tile accumulators spill. out_mean store CACHED (r8: nt on 4B scalars
// = 8-16x write amplification). hq loads CACHED. out_new store nt (r11 best).
__global__ __launch_bounds__(256, 3) void mqc_main_kernel(
    const ushort* __restrict__ xhi, const ushort* __restrict__ xlo,
    const ushort* __restrict__ whi, const ushort* __restrict__ wlo,
    const float* __restrict__ hq,
    float* __restrict__ out_mean, float* __restrict__ out_new)
{
    // one k-chunk (16 koct = 128 k) of B fragments: 4 ntiles x 16 kl x 16 l16 x 8
    __shared__ ushort sBh[8192], sBl[8192];    // 16 KiB + 16 KiB

    const int t     = threadIdx.x;
    const int lane  = t & 63;
    const int w     = t >> 6;           // wave 0..3 -> rows w*32..w*32+31
    const int lquad = lane >> 4;        // 0..3
    const int l16   = lane & 15;

    // XCD-clustered bijective block mapping (4096 = 8 xcd * 4 rowg * 128 colg)
    const int wgid = blockIdx.x;
    const int xcd  = wgid & 7;
    const int q    = wgid >> 3;
    const int rowg = (xcd << 2) | (q & 3);   // 0..31
    const int colg = q >> 2;                 // 0..127
    const int row0 = rowg * BM;
    const int col0 = colg * BN;
    const int btile0 = (row0 >> 4) + w * 2;
    const int ntile0 = col0 >> 4;

    f32x4 acc[2][4] = {};               // [mi][ni]; D[n][b]: row=n, col=b

    // Stage one k-chunk of B (both planes, 32 KB) via global_load_lds w16.
    #define STAGE(KOCT0) {                                                          \
        _Pragma("unroll")                                                           \
        for (int itc = 0; itc < 8; ++itc) {                                         \
            const int c  = itc * 4 + w;                                             \
            const int nt = (c >> 2) & 3;                                            \
            const int kl = (c & 3) * 4 + (lane >> 4);                               \
            const ushort* srcp = ((c >> 4) ? wlo : whi)                             \
                + ((size_t)(ntile0 + nt) * 32 + (KOCT0) + kl) * 128 + (lane & 15) * 8; \
            ushort* dstp = ((c >> 4) ? sBl : sBh) + nt * 2048 + (c & 3) * 512;      \
            __builtin_amdgcn_global_load_lds((as1_uint*)srcp, (as3_uint*)dstp,      \
                                             16, 0, 0);                             \
        }                                                                           \
    }

    // prefetch A fragments for 2 k-steps (SL0, SL0+1) of chunk KOCT0 into regs
    #define APREF(AH, AL, KOCT0, SL0) {                                             \
        _Pragma("unroll")                                                           \
        for (int s = 0; s < 2; ++s) {                                               \
            const int koct = (KOCT0) + ((SL0) + s) * 4 + lquad;                     \
            _Pragma("unroll")                                                       \
            for (int mi = 0; mi < 2; ++mi) {                                        \
                const size_t o = ((size_t)(btile0 + mi) * 32 + koct) * 128 + l16 * 8; \
                AH[s][mi] = *(const bf16x8*)(xhi + o);                              \
                AL[s][mi] = *(const bf16x8*)(xlo + o);                              \
            }                                                                       \
        }                                                                           \
    }

    // 2 MFMA k-steps (SL0, SL0+1) using prefetched A regs + staged B in LDS
    #define KSTEP2(AH, AL, SL0) {                                                   \
        _Pragma("unroll")                                                           \
        for (int s = 0; s < 2; ++s) {                                               \
            const int bidx = (((SL0) + s) * 4 + lquad) * 128 + l16 * 8;             \
            bf16x8 bH[4], bL[4];                                                    \
            _Pragma("unroll")                                                       \
            for (int ni = 0; ni < 4; ++ni) {                                        \
                bH[ni] = *(const bf16x8*)(sBh + ni * 2048 + bidx);                  \
                bL[ni] = *(const bf16x8*)(sBl + ni * 2048 + bidx);                  \
            }                                                                       \
            _Pragma("unroll")                                                       \
            for (int mi = 0; mi < 2; ++mi)                                          \
                _Pragma("unroll")                                                   \
                for (int ni = 0; ni < 4; ++ni)                                      \
                    acc[mi][ni] = __builtin_amdgcn_mfma_f32_16x16x32_bf16(bH[ni], AH[s][mi], acc[mi][ni], 0, 0, 0); \
            _Pragma("unroll")                                                       \
            for (int mi = 0; mi < 2; ++mi)                                          \
                _Pragma("unroll")                                                   \
                for (int ni = 0; ni < 4; ++ni)                                      \
                    acc[mi][ni] = __builtin_amdgcn_mfma_f32_16x16x32_bf16(bH[ni], AL[s][mi], acc[mi][ni], 0, 0, 0); \
            _Pragma("unroll")                                                       \
            for (int mi = 0; mi < 2; ++mi)                                          \
                _Pragma("unroll")                                                   \
                for (int ni = 0; ni < 4; ++ni)                                      \
                    acc[mi][ni] = __builtin_amdgcn_mfma_f32_16x16x32_bf16(bL[ni], AH[s][mi], acc[mi][ni], 0, 0, 0); \
        }                                                                           \
    }

    bf16x8 AaH[2][2], AaL[2][2], AbH[2][2], AbL[2][2];
    fvec4 hv[2][4];

    // ---- chunk 0 (koct 0..15) ----
    STAGE(0);
    APREF(AaH, AaL, 0, 0);          // A for ksteps 0,1 — in flight with DMA
    // hq prefetch hoisted here: its ~900cyc latency folds into the same
    // vmcnt-drain the barrier pays for the DMA, then chunk-0's 96 MFMAs.
    #pragma unroll
    for (int mi = 0; mi < 2; ++mi) {
        const int b = row0 + w * 32 + mi * 16 + l16;
        #pragma unroll
        for (int ni = 0; ni < 4; ++ni) {
            const int n = col0 + ni * 16 + lquad * 4;
            hv[mi][ni] = *(const fvec4*)&hq[(size_t)b * NCOL + n];
        }
    }
    __syncthreads();                // drains DMA + A loads + hv loads
    APREF(AbH, AbL, 0, 2);          // A for ksteps 2,3 — hidden under KSTEP2
    KSTEP2(AaH, AaL, 0);
    KSTEP2(AbH, AbL, 2);
    __syncthreads();                // chunk-0 LDS reads done before overwrite
    // ---- chunk 1 (koct 16..31) ----
    STAGE(16);
    APREF(AaH, AaL, 16, 0);
    __syncthreads();
    APREF(AbH, AbL, 16, 2);
    KSTEP2(AaH, AaL, 0);
    KSTEP2(AbH, AbL, 2);
    #undef STAGE
    #undef APREF
    #undef KSTEP2

    // ---- fused epilogue: tanh(C + 0.9*h), nt out_new store, cached out_mean.
    //      D[n][b]: n = col0+ni*16+4*lquad+reg, b = row0+w*32+mi*16+l16
    #pragma unroll
    for (int mi = 0; mi < 2; ++mi) {
        const int b = row0 + w * 32 + mi * 16 + l16;
        #pragma unroll
        for (int ni = 0; ni < 4; ++ni) {
            const int n = col0 + ni * 16 + lquad * 4;
            fvec4 ov;
            ov.x = tanh_fast(__builtin_fmaf(0.9f, hv[mi][ni].x, acc[mi][ni][0]));
            ov.y = tanh_fast(__builtin_fmaf(0.9f, hv[mi][ni].y, acc[mi][ni][1]));
            ov.z = tanh_fast(__builtin_fmaf(0.9f, hv[mi][ni].z, acc[mi][ni][2]));
            ov.w = tanh_fast(__builtin_fmaf(0.9f, hv[mi][ni].w, acc[mi][ni][3]));
            __builtin_nontemporal_store(ov, (fvec4*)&out_new[(size_t)b * NCOL + n]);
            float s = (ov.x + ov.y) + (ov.z + ov.w);
            s += __shfl_xor(s, 16);
            s += __shfl_xor(s, 32);
            if (lquad == 0)
                out_mean[(size_t)b * HID + (col0 >> 4) + ni] = s * 0.0625f;
        }
    }
}

// ================= fallback (round-5 proven kernel, used if ws too small) ======
#define BKF 64
__device__ __forceinline__ int swz(int row, int byteoff) {
    return byteoff ^ ((((row & 7) ^ ((row >> 3) & 7))) << 4);
}
__global__ __launch_bounds__(256, 4) void mqc_fallback_kernel(
    const float* __restrict__ x, const float* __restrict__ hq,
    const float* __restrict__ W,
    float* __restrict__ out_mean, float* __restrict__ out_new)
{
    __shared__ char sB[2 * BN * BKF * 2];
    char* const sB_hi = sB;
    char* const sB_lo = sB + BN * BKF * 2;
    const int t = threadIdx.x, lane = t & 63, w = t >> 6;
    const int lquad = lane >> 4, l16 = lane & 15;
    const int row0 = blockIdx.x * BM, col0 = blockIdx.y * BN;
    const int k0 = (t >> 4) * 4, n0 = (t & 15) * 4;
    f32x4 acc[2][4] = {};
    for (int kt = 0; kt < IN_DIM / BKF; ++kt) {
        float4 ax[2][2][2];
        #pragma unroll
        for (int mi = 0; mi < 2; ++mi)
            #pragma unroll
            for (int ks = 0; ks < 2; ++ks) {
                const float* p = &x[(size_t)(row0 + w * 32 + mi * 16 + l16) * IN_DIM
                                    + kt * BKF + ks * 32 + lquad * 8];
                ax[mi][ks][0] = *(const float4*)(p);
                ax[mi][ks][1] = *(const float4*)(p + 4);
            }
        float4 wrow[4];
        #pragma unroll
        for (int r = 0; r < 4; ++r)
            wrow[r] = *(const float4*)(&W[(size_t)(kt * BKF + k0 + r) * NCOL + col0 + n0]);
        #pragma unroll
        for (int c = 0; c < 4; ++c) {
            const float f0 = ((const float*)&wrow[0])[c];
            const float f1 = ((const float*)&wrow[1])[c];
            const float f2 = ((const float*)&wrow[2])[c];
            const float f3 = ((const float*)&wrow[3])[c];
            uint2 hv2, lv2;
            hv2.x = pack_hi(f0, f1); hv2.y = pack_hi(f2, f3);
            lv2.x = pack_hi(f0 - hi_part(f0), f1 - hi_part(f1));
            lv2.y = pack_hi(f2 - hi_part(f2), f3 - hi_part(f3));
            const int off = swz(n0 + c, (n0 + c) * (BKF * 2) + k0 * 2);
            *(uint2*)(sB_hi + off) = hv2;
            *(uint2*)(sB_lo + off) = lv2;
        }
        __syncthreads();
        #pragma unroll
        for (int ks = 0; ks < 2; ++ks) {
            bf16x8 aH[2], aL[2];
            #pragma unroll
            for (int mi = 0; mi < 2; ++mi) {
                uint4 h, l;
                split8((const float*)&ax[mi][ks][0], h, l);
                aH[mi] = __builtin_bit_cast(bf16x8, h);
                aL[mi] = __builtin_bit_cast(bf16x8, l);
            }
            const int kb = ks * 64 + lquad * 16;
            bf16x8 bH[4], bL[4];
            #pragma unroll
            for (int ni = 0; ni < 4; ++ni) {
                const int row = ni * 16 + l16;
                bH[ni] = *(const bf16x8*)(sB_hi + swz(row, row * (BKF * 2) + kb));
            }
            #pragma unroll
            for (int mi = 0; mi < 2; ++mi)
                #pragma unroll
                for (int ni = 0; ni < 4; ++ni)
                    acc[mi][ni] = __builtin_amdgcn_mfma_f32_16x16x32_bf16(bH[ni], aH[mi], acc[mi][ni], 0, 0, 0);
            #pragma unroll
            for (int mi = 0; mi < 2; ++mi)
                #pragma unroll
                for (int ni = 0; ni < 4; ++ni)
                    acc[mi][ni] = __builtin_amdgcn_mfma_f32_16x16x32_bf16(bH[ni], aL[mi], acc[mi][ni], 0, 0, 0);
            #pragma unroll
            for (int ni = 0; ni < 4; ++ni) {
                const int row = ni * 16 + l16;
                bL[ni] = *(const bf16x8*)(sB_lo + swz(row, row * (BKF * 2) + kb));
            }
            #pragma unroll
            for (int mi = 0; mi < 2; ++mi)
                #pragma unroll
                for (int ni = 0; ni < 4; ++ni)
                    acc[mi][ni] = __builtin_amdgcn_mfma_f32_16x16x32_bf16(bL[ni], aH[mi], acc[mi][ni], 0, 0, 0);
        }
        __syncthreads();
    }
    #pragma unroll
    for (int mi = 0; mi < 2; ++mi) {
        const int b = row0 + w * 32 + mi * 16 + l16;
        #pragma unroll
        for (int ni = 0; ni < 4; ++ni) {
            const int n = col0 + ni * 16 + lquad * 4;
            const float4 hv = *(const float4*)(&hq[(size_t)b * NCOL + n]);
            float4 ov;
            ov.x = tanh_fast(__builtin_fmaf(0.9f, hv.x, acc[mi][ni][0]));
            ov.y = tanh_fast(__builtin_fmaf(0.9f, hv.y, acc[mi][ni][1]));
            ov.z = tanh_fast(__builtin_fmaf(0.9f, hv.z, acc[mi][ni][2]));
            ov.w = tanh_fast(__builtin_fmaf(0.9f, hv.w, acc[mi][ni][3]));
            *(float4*)(&out_new[(size_t)b * NCOL + n]) = ov;
            float s = (ov.x + ov.y) + (ov.z + ov.w);
            s += __shfl_xor(s, 16);
            s += __shfl_xor(s, 32);
            if (lquad == 0)
                out_mean[(size_t)b * HID + (col0 >> 4) + ni] = s * 0.0625f;
        }
    }
}

extern "C" void kernel_launch(void* const* d_in, const int* in_sizes, int n_in,
                              void* d_out, int out_size, void* d_ws, size_t ws_size,
                              hipStream_t stream) {
    const float* x  = (const float*)d_in[0];   // [4096, 256]
    const float* hq = (const float*)d_in[1];   // [4096, 512, 16]
    const float* W  = (const float*)d_in[2];   // [256, 512, 16]

    float* out_mean = (float*)d_out;                          // [4096, 512]
    float* out_new  = (float*)d_out + (size_t)BATCH * HID;    // [4096, 512, 16]

    if (ws_size >= WS_NEED) {
        ushort* whi = (ushort*)d_ws;
        ushort* wlo = whi + W_ELEMS;
        ushort* xhi = wlo + W_ELEMS;
        ushort* xlo = xhi + X_ELEMS;
        prep_w_kernel<<<dim3(NCOL / 256, IN_DIM / 8), 256, 0, stream>>>(W, whi, wlo);
        prep_x_kernel<<<dim3(BATCH / 256, IN_DIM / 8), 256, 0, stream>>>(x, xhi, xlo);
        mqc_main_kernel<<<dim3(BATCH * NCOL / (BM * BN)), 256, 0, stream>>>(
            xhi, xlo, whi, wlo, hq, out_mean, out_new);
    } else {
        mqc_fallback_kernel<<<dim3(BATCH / BM, NCOL / BN), 256, 0, stream>>>(
            x, hq, W, out_mean, out_new);
    }
}